// Round 7
// baseline (410.604 us; speedup 1.0000x reference)
//
#include <hip/hip_runtime.h>

// HeteroSAGE on MI355X — round 7: un-merged setup/count, 8-edge-ILP count,
// 4-edge-ILP fill (CSR build was latency-bound at 1 item/thread).
//
// Pipeline (memset + 7 dispatches):
//   0. memsetAsync: cnt (4N ints) + desc (257 u64) -> 0
//   1. setup: x->bf16, fold weights, build Wz bf16
//   2. count (y=4): 8 edges/thread, 8 independent atomic-with-return chains
//   3. scan: single-kernel decoupled-lookback exclusive prefix
//   4. fill (y=4): 4 edges/thread, col[rowptr[d]+rank[e]] = src (no atomics)
//   5. agg (y=4): per-(node,rel) mean, quarter-wave, 1-op unpacks -> aggb bf16
//   6. gemm0z (y=2): LDS-staged A, 16-MFMA k-iters; h->LDS bf16; z via MFMA
//   7. l1_agg (y=2): 8 lanes/node CSR walk, xor-reduce, out += mean(z)

#define DIN 128
#define DH  256
#define LDSA 136    // A-tile row stride (shorts): 128+8 pad
#define LDSH 264    // h-tile row stride (shorts): 256+8 pad

typedef __attribute__((ext_vector_type(8))) short bf16x8;
typedef __attribute__((ext_vector_type(4))) float f32x4;

__device__ __forceinline__ float blo(unsigned u) {           // even element
    return __uint_as_float(u << 16);
}
__device__ __forceinline__ float bhi(unsigned u) {           // odd element
    return __uint_as_float(u & 0xffff0000u);
}
__device__ __forceinline__ unsigned short f2bf(float f) {
    unsigned int u = __float_as_uint(f);
    u = (u + 0x7fffu + ((u >> 16) & 1u)) >> 16;   // RNE
    return (unsigned short)u;
}

// ---------------- setup ----------------
__global__ __launch_bounds__(256) void setup_kernel(
    const float* __restrict__ x_tx, const float* __restrict__ x_addr,
    const float* __restrict__ Wl0_tt, const float* __restrict__ Wl0_aa,
    const float* __restrict__ Wl0_at, const float* __restrict__ Wl0_ta,
    const float* __restrict__ Wr0_tt, const float* __restrict__ Wr0_aa,
    const float* __restrict__ Wr0_at, const float* __restrict__ Wr0_ta,
    const float* __restrict__ bl0_tt, const float* __restrict__ bl0_aa,
    const float* __restrict__ bl0_at, const float* __restrict__ bl0_ta,
    const float* __restrict__ Wl1_tt, const float* __restrict__ Wl1_aa,
    const float* __restrict__ Wl1_at, const float* __restrict__ Wl1_ta,
    const float* __restrict__ Wr1_tt, const float* __restrict__ Wr1_aa,
    const float* __restrict__ Wr1_at, const float* __restrict__ Wr1_ta,
    const float* __restrict__ bl1_tt, const float* __restrict__ bl1_aa,
    const float* __restrict__ bl1_at, const float* __restrict__ bl1_ta,
    unsigned short* __restrict__ xb_tx, unsigned short* __restrict__ xb_ad,
    unsigned short* __restrict__ wb_tt, unsigned short* __restrict__ wb_aa,
    unsigned short* __restrict__ wb_at, unsigned short* __restrict__ wb_ta,
    unsigned short* __restrict__ wr0c_tx, unsigned short* __restrict__ wr0c_ad,
    float* __restrict__ b0c, unsigned short* __restrict__ wzb,
    float* __restrict__ b1c, int N)
{
    int i = blockIdx.x * blockDim.x + threadIdx.x;
    int nconv = N * DIN / 8;                 // 800000
    if (i < nconv) {
        {
            const float4* p = (const float4*)(x_tx + (size_t)i * 8);
            float4 a = p[0], b = p[1];
            uint4 o;
            o.x = (unsigned)f2bf(a.x) | ((unsigned)f2bf(a.y) << 16);
            o.y = (unsigned)f2bf(a.z) | ((unsigned)f2bf(a.w) << 16);
            o.z = (unsigned)f2bf(b.x) | ((unsigned)f2bf(b.y) << 16);
            o.w = (unsigned)f2bf(b.z) | ((unsigned)f2bf(b.w) << 16);
            *(uint4*)(xb_tx + (size_t)i * 8) = o;
        }
        {
            const float4* p = (const float4*)(x_addr + (size_t)i * 8);
            float4 a = p[0], b = p[1];
            uint4 o;
            o.x = (unsigned)f2bf(a.x) | ((unsigned)f2bf(a.y) << 16);
            o.y = (unsigned)f2bf(a.z) | ((unsigned)f2bf(a.w) << 16);
            o.z = (unsigned)f2bf(b.x) | ((unsigned)f2bf(b.y) << 16);
            o.w = (unsigned)f2bf(b.z) | ((unsigned)f2bf(b.w) << 16);
            *(uint4*)(xb_ad + (size_t)i * 8) = o;
        }
    }
    if (i < DH * DIN) {
        wb_tt[i] = f2bf(Wl0_tt[i]);
        wb_aa[i] = f2bf(Wl0_aa[i]);
        wb_at[i] = f2bf(Wl0_at[i]);
        wb_ta[i] = f2bf(Wl0_ta[i]);
        wr0c_tx[i] = f2bf(Wr0_tt[i] + Wr0_at[i]);
        wr0c_ad[i] = f2bf(Wr0_aa[i] + Wr0_ta[i]);
    }
    if (i < DH) {
        b0c[i]      = bl0_tt[i] + bl0_at[i];
        b0c[DH + i] = bl0_aa[i] + bl0_ta[i];
    }
    if (i < 2 * 16 * DH) {                    // wzb: [type][16][256] bf16, rows>=6 zero
        int type = i >> 12;
        int rem = i & 4095;
        int r = rem >> 8;
        int c = rem & 255;
        float v = 0.f;
        if (r < 6) {
            const float* A = type ? Wl1_aa : Wl1_tt;
            const float* B = type ? Wl1_at : Wl1_ta;
            if (r == 0) v = A[c];
            else if (r == 1) v = A[DH + c];
            else if (r == 2) v = B[c];
            else if (r == 3) v = B[DH + c];
            else if (r == 4) v = type ? (Wr1_aa[c] + Wr1_ta[c]) : (Wr1_tt[c] + Wr1_at[c]);
            else             v = type ? (Wr1_aa[DH + c] + Wr1_ta[DH + c])
                                      : (Wr1_tt[DH + c] + Wr1_at[DH + c]);
        }
        wzb[i] = f2bf(v);
    }
    if (i < 2) {
        b1c[i]     = bl1_tt[i] + bl1_at[i];
        b1c[2 + i] = bl1_aa[i] + bl1_ta[i];
    }
}

// ---------------- count: 8 edges/thread, independent atomic chains ----------
__global__ __launch_bounds__(256) void count_kernel(
    const int* __restrict__ e0, const int* __restrict__ e1,
    const int* __restrict__ e2, const int* __restrict__ e3,
    int* __restrict__ cnt, int* __restrict__ rank, int E, int N)
{
    int r = blockIdx.y;
    const int* e = (r == 0) ? e0 : (r == 1) ? e1 : (r == 2) ? e2 : e3;
    int base = (blockIdx.x * 256 + threadIdx.x) * 8;
    int* cb = cnt + r * N;
    int* rk = rank + (size_t)r * E;
    if (base + 8 <= E) {
        int4 d0 = *(const int4*)(e + E + base);
        int4 d1 = *(const int4*)(e + E + base + 4);
        int4 r0, r1;
        r0.x = atomicAdd(&cb[d0.x], 1);
        r0.y = atomicAdd(&cb[d0.y], 1);
        r0.z = atomicAdd(&cb[d0.z], 1);
        r0.w = atomicAdd(&cb[d0.w], 1);
        r1.x = atomicAdd(&cb[d1.x], 1);
        r1.y = atomicAdd(&cb[d1.y], 1);
        r1.z = atomicAdd(&cb[d1.z], 1);
        r1.w = atomicAdd(&cb[d1.w], 1);
        *(int4*)(rk + base) = r0;
        *(int4*)(rk + base + 4) = r1;
    } else {
        for (int i = base; i < E; ++i)
            rk[i] = atomicAdd(&cb[e[E + i]], 1);
    }
}

// single-kernel decoupled-lookback exclusive scan (ticket-ordered)
__global__ __launch_bounds__(1024) void scan_kernel(
    const int* __restrict__ cnt, int* __restrict__ excl,
    unsigned long long* __restrict__ desc, int n)
{
    __shared__ int sdata[1024];
    __shared__ int sseg;
    __shared__ int sprev;
    if (threadIdx.x == 0) sseg = (int)atomicAdd(&desc[256], 1ULL);
    __syncthreads();
    int seg = sseg;
    int i = seg * 1024 + threadIdx.x;
    int v = (i < n) ? cnt[i] : 0;
    sdata[threadIdx.x] = v;
    __syncthreads();
    for (int off = 1; off < 1024; off <<= 1) {
        int t = (threadIdx.x >= off) ? sdata[threadIdx.x - off] : 0;
        __syncthreads();
        sdata[threadIdx.x] += t;
        __syncthreads();
    }
    if (threadIdx.x == 0) {
        int total = sdata[1023];
        int prev = 0;
        if (seg == 0) {
            atomicExch(&desc[0], ((unsigned long long)(unsigned)total << 2) | 2ULL);
        } else {
            atomicExch(&desc[seg], ((unsigned long long)(unsigned)total << 2) | 1ULL);
            int j = seg - 1;
            for (;;) {
                unsigned long long d = atomicAdd(&desc[j], 0ULL);
                unsigned st = (unsigned)(d & 3ULL);
                if (st == 0u) continue;
                prev += (int)(d >> 2);
                if (st == 2u) break;
                --j;
            }
            atomicExch(&desc[seg],
                       ((unsigned long long)(unsigned)(prev + total) << 2) | 2ULL);
        }
        sprev = prev;
    }
    __syncthreads();
    if (i < n) excl[i] = sprev + sdata[threadIdx.x] - v;
}

// ---------------- fill: 4 edges/thread, no atomics ----------------
__global__ __launch_bounds__(256) void fill_kernel(
    const int* __restrict__ e0, const int* __restrict__ e1,
    const int* __restrict__ e2, const int* __restrict__ e3,
    const int* __restrict__ rowptr, const int* __restrict__ rank,
    int* __restrict__ col, int E, int N)
{
    int r = blockIdx.y;
    const int* e = (r == 0) ? e0 : (r == 1) ? e1 : (r == 2) ? e2 : e3;
    const int* rp = rowptr + r * N;
    const int* rk = rank + (size_t)r * E;
    int base = (blockIdx.x * 256 + threadIdx.x) * 4;
    if (base + 4 <= E) {
        int4 s = *(const int4*)(e + base);
        int4 d = *(const int4*)(e + E + base);
        int4 rr = *(const int4*)(rk + base);
        int p0 = rp[d.x], p1 = rp[d.y], p2 = rp[d.z], p3 = rp[d.w];
        col[p0 + rr.x] = s.x;
        col[p1 + rr.y] = s.y;
        col[p2 + rr.z] = s.z;
        col[p3 + rr.w] = s.w;
    } else {
        for (int i = base; i < E; ++i)
            col[rp[e[E + i]] + rk[i]] = e[i];
    }
}

// ---------------- layer-0 mean aggregation: cheap unpack, 32-bit addr ----------
__global__ __launch_bounds__(256) void agg_kernel(
    const unsigned short* __restrict__ xb_tx, const unsigned short* __restrict__ xb_ad,
    const int* __restrict__ rowptr, const int* __restrict__ cnt,
    const int* __restrict__ col, unsigned short* __restrict__ aggb, int N)
{
    int r = blockIdx.y;                        // 0=tt 1=aa 2=at 3=ta
    const uint4* xs = (const uint4*)((r == 0 || r == 3) ? xb_tx : xb_ad);
    int wave = threadIdx.x >> 6;
    int l    = threadIdx.x & 63;
    int node = blockIdx.x * 4 + wave;
    if (node >= N) return;
    int base = rowptr[r * N + node];
    int c    = cnt[r * N + node];
    const int* cl = col + base;
    int q = l >> 4;
    int d = l & 15;
    float aE[4] = {}, aO[4] = {}, bE[4] = {}, bO[4] = {};
    int e0 = 0;
    for (; e0 + 8 <= c; e0 += 8) {
        unsigned iA = ((unsigned)cl[e0 + q] << 4) + d;
        unsigned iB = ((unsigned)cl[e0 + 4 + q] << 4) + d;
        uint4 uA = xs[iA];
        uint4 uB = xs[iB];
        aE[0] += blo(uA.x); aO[0] += bhi(uA.x);
        aE[1] += blo(uA.y); aO[1] += bhi(uA.y);
        aE[2] += blo(uA.z); aO[2] += bhi(uA.z);
        aE[3] += blo(uA.w); aO[3] += bhi(uA.w);
        bE[0] += blo(uB.x); bO[0] += bhi(uB.x);
        bE[1] += blo(uB.y); bO[1] += bhi(uB.y);
        bE[2] += blo(uB.z); bO[2] += bhi(uB.z);
        bE[3] += blo(uB.w); bO[3] += bhi(uB.w);
    }
    for (; e0 < c; e0 += 4) {
        int e = e0 + q;
        if (e < c) {
            unsigned iA = ((unsigned)cl[e] << 4) + d;
            uint4 u = xs[iA];
            aE[0] += blo(u.x); aO[0] += bhi(u.x);
            aE[1] += blo(u.y); aO[1] += bhi(u.y);
            aE[2] += blo(u.z); aO[2] += bhi(u.z);
            aE[3] += blo(u.w); aO[3] += bhi(u.w);
        }
    }
#pragma unroll
    for (int j = 0; j < 4; ++j) {
        aE[j] += bE[j];
        aO[j] += bO[j];
        aE[j] += __shfl_xor(aE[j], 16, 64);
        aE[j] += __shfl_xor(aE[j], 32, 64);
        aO[j] += __shfl_xor(aO[j], 16, 64);
        aO[j] += __shfl_xor(aO[j], 32, 64);
    }
    if (q == 0) {
        float sc = 1.0f / fmaxf((float)c, 1.0f);
        uint4 o;
        o.x = (unsigned)f2bf(aE[0] * sc) | ((unsigned)f2bf(aO[0] * sc) << 16);
        o.y = (unsigned)f2bf(aE[1] * sc) | ((unsigned)f2bf(aO[1] * sc) << 16);
        o.z = (unsigned)f2bf(aE[2] * sc) | ((unsigned)f2bf(aO[2] * sc) << 16);
        o.w = (unsigned)f2bf(aE[3] * sc) | ((unsigned)f2bf(aO[3] * sc) << 16);
        *(uint4*)(aggb + ((size_t)r * N + node) * DIN + d * 8) = o;
    }
}

// ---------------- gemm0 + fused layer-1 transform, LDS-staged A ----------------
__global__ __launch_bounds__(256) void gemm0z_kernel(
    const unsigned short* __restrict__ xb_tx, const unsigned short* __restrict__ xb_ad,
    const unsigned short* __restrict__ aggb,
    const unsigned short* __restrict__ wb_tt, const unsigned short* __restrict__ wb_at,
    const unsigned short* __restrict__ wr0c_tx,
    const unsigned short* __restrict__ wb_aa, const unsigned short* __restrict__ wb_ta,
    const unsigned short* __restrict__ wr0c_ad,
    const float* __restrict__ b0c, const unsigned short* __restrict__ wzb,
    const float* __restrict__ b1c,
    float* __restrict__ z, float* __restrict__ outp, int N)
{
    __shared__ unsigned short lds[3 * 64 * LDSA];   // 52224 B; h (64*LDSH) aliases it
    const int type = blockIdx.y;
    const unsigned short* xself = type ? xb_ad : xb_tx;
    const unsigned short* A0 = aggb + (size_t)(type ? 1 : 0) * N * DIN;  // aa / tt
    const unsigned short* A1 = aggb + (size_t)(type ? 3 : 2) * N * DIN;  // ta / at
    const unsigned short* W0 = type ? wb_aa   : wb_tt;
    const unsigned short* W1 = type ? wb_ta   : wb_at;
    const unsigned short* W2 = type ? wr0c_ad : wr0c_tx;
    const float* bias = b0c + type * DH;
    float* zA = type ? (z + (size_t)1 * N * 2) : z;                       // aa / tt
    float* zB = type ? (z + (size_t)2 * N * 2) : (z + (size_t)3 * N * 2); // at / ta
    float* outSelf = outp + (size_t)type * N * 2;

    const int t  = threadIdx.x;
    const int wv = t >> 6;
    const int l  = t & 63;
    const int q  = l >> 4;
    const int lr = l & 15;
    const int m0 = blockIdx.x * 64;
    const int n0 = wv * 64;

    // ---- phase 1: stage A tiles (3072 chunks of 16B; 12 per thread) ----
    {
        const uint4* As[3] = {(const uint4*)A0, (const uint4*)A1, (const uint4*)xself};
#pragma unroll
        for (int i = 0; i < 12; ++i) {
            int cid = i * 256 + t;
            int seg = cid >> 10;
            int rem = cid & 1023;
            int row = rem >> 4;
            int ch  = rem & 15;
            int gr = m0 + row; if (gr >= N) gr = N - 1;
            uint4 v = As[seg][((unsigned)gr << 4) + ch];
            *(uint4*)&lds[(seg * 64 + row) * LDSA + ch * 8] = v;
        }
    }
    __syncthreads();

    // ---- phase 2: K-loop ----
    f32x4 accm[4][4] = {};
    {
        const unsigned short* Ws[3] = {W0, W1, W2};
        for (int seg = 0; seg < 3; ++seg) {
            const unsigned short* W = Ws[seg];
            const unsigned short* la = &lds[(seg * 64 + lr) * LDSA + q * 8];
            const unsigned short* pb0 = W + (unsigned)(n0 + lr) * DIN + q * 8;
            const unsigned short* pb1 = W + (unsigned)(n0 + 16 + lr) * DIN + q * 8;
            const unsigned short* pb2 = W + (unsigned)(n0 + 32 + lr) * DIN + q * 8;
            const unsigned short* pb3 = W + (unsigned)(n0 + 48 + lr) * DIN + q * 8;
#pragma unroll
            for (int k = 0; k < DIN; k += 32) {
                bf16x8 b0 = *(const bf16x8*)(pb0 + k);
                bf16x8 b1 = *(const bf16x8*)(pb1 + k);
                bf16x8 b2 = *(const bf16x8*)(pb2 + k);
                bf16x8 b3 = *(const bf16x8*)(pb3 + k);
#pragma unroll
                for (int mt = 0; mt < 4; ++mt) {
                    bf16x8 a = *(const bf16x8*)(la + mt * 16 * LDSA + k);
                    accm[mt][0] = __builtin_amdgcn_mfma_f32_16x16x32_bf16(a, b0, accm[mt][0], 0, 0, 0);
                    accm[mt][1] = __builtin_amdgcn_mfma_f32_16x16x32_bf16(a, b1, accm[mt][1], 0, 0, 0);
                    accm[mt][2] = __builtin_amdgcn_mfma_f32_16x16x32_bf16(a, b2, accm[mt][2], 0, 0, 0);
                    accm[mt][3] = __builtin_amdgcn_mfma_f32_16x16x32_bf16(a, b3, accm[mt][3], 0, 0, 0);
                }
            }
        }
    }
    __syncthreads();   // all LDS-A reads done before h overwrites

    // ---- phase 3: h = relu(acc + bias) -> LDS bf16 ----
    {
        float bias_nt[4];
#pragma unroll
        for (int nt = 0; nt < 4; ++nt) bias_nt[nt] = bias[n0 + nt * 16 + lr];
#pragma unroll
        for (int mt = 0; mt < 4; ++mt) {
#pragma unroll
            for (int nt = 0; nt < 4; ++nt) {
                int colc = n0 + nt * 16 + lr;
#pragma unroll
                for (int rr = 0; rr < 4; ++rr) {
                    int row = mt * 16 + q * 4 + rr;
                    lds[row * LDSH + colc] =
                        f2bf(fmaxf(accm[mt][nt][rr] + bias_nt[nt], 0.f));
                }
            }
        }
    }
    __syncthreads();

    // ---- phase 4: z = h @ Wz^T (one 16-row m-tile per wave) ----
    {
        const unsigned short* wz = wzb + (size_t)type * 16 * DH;
        f32x4 az = {};
        const unsigned short* la = &lds[(wv * 16 + lr) * LDSH + q * 8];
        const unsigned short* pb = wz + lr * DH + q * 8;
#pragma unroll
        for (int k = 0; k < DH; k += 32) {
            bf16x8 a = *(const bf16x8*)(la + k);
            bf16x8 b = *(const bf16x8*)(pb + k);
            az = __builtin_amdgcn_mfma_f32_16x16x32_bf16(a, b, az, 0, 0, 0);
        }
        if (lr < 6) {
#pragma unroll
            for (int reg = 0; reg < 4; ++reg) {
                int node = m0 + wv * 16 + q * 4 + reg;
                if (node < N) {
                    float v = az[reg];
                    if (lr < 2)      zA[node * 2 + lr] = v;
                    else if (lr < 4) zB[node * 2 + lr - 2] = v;
                    else             outSelf[node * 2 + lr - 4] = v + b1c[type * 2 + lr - 4];
                }
            }
        }
    }
}

// ---------------- layer-1 aggregate (y=2): 8 lanes per node ----------------
__global__ __launch_bounds__(256) void l1_agg_kernel(
    const int* __restrict__ rowptr, const int* __restrict__ cnt, const int* __restrict__ col,
    const float* __restrict__ z, float* __restrict__ out, int N)
{
    const int type = blockIdx.y;
    const int rA = type ? 1 : 0;
    const int rB = type ? 3 : 2;
    const float* zAp = type ? (z + (size_t)1 * N * 2) : z;
    const float* zBp = type ? (z + (size_t)3 * N * 2) : (z + (size_t)2 * N * 2);
    float* outp = out + (size_t)type * N * 2;

    const int t = threadIdx.x;
    const int wave = t >> 6;
    const int l = t & 63;
    const int sub = l >> 3;       // node within wave's 8
    const int es  = l & 7;        // edge slot
    int node = blockIdx.x * 32 + wave * 8 + sub;
    bool valid = node < N;

    float ax = 0.f, ay = 0.f;
#pragma unroll
    for (int ri = 0; ri < 2; ++ri) {
        int rel = ri ? rB : rA;
        const float* zp = ri ? zBp : zAp;
        int b = 0, c = 0;
        if (valid) { b = rowptr[rel * N + node]; c = cnt[rel * N + node]; }
        const int* cl = col + b;
        float sx = 0.f, sy = 0.f;
        for (int e = es; e < c; e += 8) {
            int s = cl[e];
            float2 v = *(const float2*)(zp + (size_t)s * 2);
            sx += v.x; sy += v.y;
        }
        sx += __shfl_xor(sx, 1, 64); sy += __shfl_xor(sy, 1, 64);
        sx += __shfl_xor(sx, 2, 64); sy += __shfl_xor(sy, 2, 64);
        sx += __shfl_xor(sx, 4, 64); sy += __shfl_xor(sy, 4, 64);
        float sc = 1.0f / fmaxf((float)c, 1.0f);
        ax += sx * sc; ay += sy * sc;
    }
    if (valid && es == 0) {
        float2 o = *(float2*)(outp + (size_t)node * 2);   // self term from gemm0z
        o.x += ax; o.y += ay;
        *(float2*)(outp + (size_t)node * 2) = o;
    }
}

// ---------------- launch ----------------
extern "C" void kernel_launch(void* const* d_in, const int* in_sizes, int n_in,
                              void* d_out, int out_size, void* d_ws, size_t ws_size,
                              hipStream_t stream)
{
    const float* x_tx   = (const float*)d_in[0];
    const float* x_addr = (const float*)d_in[1];
    const int* e_tt = (const int*)d_in[2];
    const int* e_aa = (const int*)d_in[3];
    const int* e_at = (const int*)d_in[4];
    const int* e_ta = (const int*)d_in[5];
    const float* Wl0_tt = (const float*)d_in[6];
    const float* bl0_tt = (const float*)d_in[7];
    const float* Wr0_tt = (const float*)d_in[8];
    const float* Wl0_aa = (const float*)d_in[9];
    const float* bl0_aa = (const float*)d_in[10];
    const float* Wr0_aa = (const float*)d_in[11];
    const float* Wl0_at = (const float*)d_in[12];
    const float* bl0_at = (const float*)d_in[13];
    const float* Wr0_at = (const float*)d_in[14];
    const float* Wl0_ta = (const float*)d_in[15];
    const float* bl0_ta = (const float*)d_in[16];
    const float* Wr0_ta = (const float*)d_in[17];
    const float* Wl1_tt = (const float*)d_in[18];
    const float* bl1_tt = (const float*)d_in[19];
    const float* Wr1_tt = (const float*)d_in[20];
    const float* Wl1_aa = (const float*)d_in[21];
    const float* bl1_aa = (const float*)d_in[22];
    const float* Wr1_aa = (const float*)d_in[23];
    const float* Wl1_at = (const float*)d_in[24];
    const float* bl1_at = (const float*)d_in[25];
    const float* Wr1_at = (const float*)d_in[26];
    const float* Wl1_ta = (const float*)d_in[27];
    const float* bl1_ta = (const float*)d_in[28];
    const float* Wr1_ta = (const float*)d_in[29];

    const int N = in_sizes[0] / DIN;   // 50000
    const int E = in_sizes[2] / 2;     // 400000

    size_t off = 0;
    char* base = (char*)d_ws;
    auto alloc = [&](size_t bytes) -> void* {
        void* p = base + off;
        off += (bytes + 255) & ~(size_t)255;
        return p;
    };
    int*   cnt    = (int*)  alloc((size_t)4 * N * 4);        // zeroed by memset
    unsigned long long* desc = (unsigned long long*)alloc(257 * 8);  // contiguous w/ cnt
    int*   rowptr = (int*)  alloc((size_t)4 * N * 4);
    int*   rank   = (int*)  alloc((size_t)4 * E * 4);
    int*   col    = (int*)  alloc((size_t)4 * E * 4);
    unsigned short* xb_tx = (unsigned short*)alloc((size_t)N * DIN * 2);
    unsigned short* xb_ad = (unsigned short*)alloc((size_t)N * DIN * 2);
    unsigned short* aggb  = (unsigned short*)alloc((size_t)4 * N * DIN * 2);
    float* z      = (float*)alloc((size_t)4 * N * 2 * 4);
    unsigned short* wb_tt  = (unsigned short*)alloc((size_t)DH * DIN * 2);
    unsigned short* wb_aa  = (unsigned short*)alloc((size_t)DH * DIN * 2);
    unsigned short* wb_at  = (unsigned short*)alloc((size_t)DH * DIN * 2);
    unsigned short* wb_ta  = (unsigned short*)alloc((size_t)DH * DIN * 2);
    unsigned short* wr0c_tx = (unsigned short*)alloc((size_t)DH * DIN * 2);
    unsigned short* wr0c_ad = (unsigned short*)alloc((size_t)DH * DIN * 2);
    float* b0c    = (float*)alloc((size_t)2 * DH * 4);
    unsigned short* wzb = (unsigned short*)alloc((size_t)2 * 16 * DH * 2);
    float* b1c    = (float*)alloc((size_t)2 * 2 * 4);
    (void)ws_size;

    float* outp = (float*)d_out;
    const int n4 = 4 * N;

    // 0. zero cnt + desc (contiguous in ws)
    hipMemsetAsync(cnt, 0, (((size_t)4 * N * 4 + 255) & ~(size_t)255) + 257 * 8, stream);

    // 1. setup
    {
        int nconv = N * DIN / 8;
        setup_kernel<<<(nconv + 255) / 256, 256, 0, stream>>>(
            x_tx, x_addr,
            Wl0_tt, Wl0_aa, Wl0_at, Wl0_ta,
            Wr0_tt, Wr0_aa, Wr0_at, Wr0_ta,
            bl0_tt, bl0_aa, bl0_at, bl0_ta,
            Wl1_tt, Wl1_aa, Wl1_at, Wl1_ta,
            Wr1_tt, Wr1_aa, Wr1_at, Wr1_ta,
            bl1_tt, bl1_aa, bl1_at, bl1_ta,
            xb_tx, xb_ad,
            wb_tt, wb_aa, wb_at, wb_ta, wr0c_tx, wr0c_ad,
            b0c, wzb, b1c, N);
    }
    // 2. counts + ranks (8 edges/thread)
    {
        dim3 g((E + 2047) / 2048, 4);
        count_kernel<<<g, 256, 0, stream>>>(e_tt, e_aa, e_at, e_ta, cnt, rank, E, N);
    }
    // 3. scan
    {
        int nb = (n4 + 1023) / 1024;
        scan_kernel<<<nb, 1024, 0, stream>>>(cnt, rowptr, desc, n4);
    }
    // 4. fill (4 edges/thread, no atomics)
    {
        dim3 g((E + 1023) / 1024, 4);
        fill_kernel<<<g, 256, 0, stream>>>(e_tt, e_aa, e_at, e_ta, rowptr, rank, col, E, N);
    }
    // 5. aggregation
    {
        dim3 g((N + 3) / 4, 4);
        agg_kernel<<<g, 256, 0, stream>>>(xb_tx, xb_ad, rowptr, cnt, col, aggb, N);
    }
    // 6. gemm0 + fused layer-1 transform
    {
        dim3 g((N + 63) / 64, 2);
        gemm0z_kernel<<<g, 256, 0, stream>>>(
            xb_tx, xb_ad, aggb,
            wb_tt, wb_at, wr0c_tx, wb_aa, wb_ta, wr0c_ad,
            b0c, wzb, b1c, z, outp, N);
    }
    // 7. layer-1 aggregation
    {
        dim3 g((N + 31) / 32, 2);
        l1_agg_kernel<<<g, 256, 0, stream>>>(rowptr, cnt, col, z, outp, N);
    }
}

// Round 8
// 375.288 us; speedup vs baseline: 1.0941x; 1.0941x over previous
//
#include <hip/hip_runtime.h>
#include <hip/hip_fp8.h>

// HeteroSAGE on MI355X — round 8: fp8 gather for layer-0 aggregation
// (halves the L2-miss-bound scatter traffic), 8-lane/task agg layout.
// Self-term and all GEMMs remain bf16; only the neighbor-mean gather is fp8.
//
// Pipeline (memset + 7 dispatches):
//   0. memsetAsync: cnt (4N ints) + desc (257 u64) -> 0
//   1. setup: x->bf16 + x->fp8, fold weights, build Wz bf16
//   2. count (y=4): 8 edges/thread, independent atomic-with-return chains
//   3. scan: single-kernel decoupled-lookback exclusive prefix
//   4. fill (y=4): 4 edges/thread, col[rowptr[d]+rank[e]] = src (no atomics)
//   5. agg (y=4): 8 lanes/(node,rel) task, fp8 rows, unroll-2 -> aggb bf16
//   6. gemm0z (y=2): LDS-staged A, 16-MFMA k-iters; h->LDS bf16; z via MFMA
//   7. l1_agg (y=2): 8 lanes/node CSR walk, xor-reduce, out += mean(z)

#define DIN 128
#define DH  256
#define LDSA 136    // A-tile row stride (shorts): 128+8 pad
#define LDSH 264    // h-tile row stride (shorts): 256+8 pad

typedef __attribute__((ext_vector_type(8))) short bf16x8;
typedef __attribute__((ext_vector_type(4))) float f32x4;
typedef __attribute__((ext_vector_type(2))) float f32x2;

__device__ __forceinline__ float blo(unsigned u) { return __uint_as_float(u << 16); }
__device__ __forceinline__ float bhi(unsigned u) { return __uint_as_float(u & 0xffff0000u); }
__device__ __forceinline__ unsigned short f2bf(float f) {
    unsigned int u = __float_as_uint(f);
    u = (u + 0x7fffu + ((u >> 16) & 1u)) >> 16;   // RNE
    return (unsigned short)u;
}

#if __has_builtin(__builtin_amdgcn_cvt_pk_fp8_f32) && __has_builtin(__builtin_amdgcn_cvt_pk_f32_fp8)
__device__ __forceinline__ unsigned pk_fp8(float4 a) {
    unsigned v = (unsigned)__builtin_amdgcn_cvt_pk_fp8_f32(a.x, a.y, 0, false);
    v = (unsigned)__builtin_amdgcn_cvt_pk_fp8_f32(a.z, a.w, (int)v, true);
    return v;
}
__device__ __forceinline__ void acc_fp8x4(float* a, unsigned u) {
    f32x2 f0 = __builtin_amdgcn_cvt_pk_f32_fp8((int)u, false);
    f32x2 f1 = __builtin_amdgcn_cvt_pk_f32_fp8((int)u, true);
    a[0] += f0.x; a[1] += f0.y; a[2] += f1.x; a[3] += f1.y;
}
#else
__device__ __forceinline__ unsigned pk_fp8(float4 a) {
    __hip_fp8_e4m3 v0(a.x), v1(a.y), v2(a.z), v3(a.w);
    return (unsigned)v0.__x | ((unsigned)v1.__x << 8) |
           ((unsigned)v2.__x << 16) | ((unsigned)v3.__x << 24);
}
__device__ __forceinline__ void acc_fp8x4(float* a, unsigned u) {
    __hip_fp8_e4m3 v0, v1, v2, v3;
    v0.__x = (unsigned char)(u & 0xff);
    v1.__x = (unsigned char)((u >> 8) & 0xff);
    v2.__x = (unsigned char)((u >> 16) & 0xff);
    v3.__x = (unsigned char)((u >> 24) & 0xff);
    a[0] += (float)v0; a[1] += (float)v1; a[2] += (float)v2; a[3] += (float)v3;
}
#endif

__device__ __forceinline__ void acc_fp8x16(float* a, uint4 u) {
    acc_fp8x4(a + 0,  u.x);
    acc_fp8x4(a + 4,  u.y);
    acc_fp8x4(a + 8,  u.z);
    acc_fp8x4(a + 12, u.w);
}

// ---------------- setup ----------------
__global__ __launch_bounds__(256) void setup_kernel(
    const float* __restrict__ x_tx, const float* __restrict__ x_addr,
    const float* __restrict__ Wl0_tt, const float* __restrict__ Wl0_aa,
    const float* __restrict__ Wl0_at, const float* __restrict__ Wl0_ta,
    const float* __restrict__ Wr0_tt, const float* __restrict__ Wr0_aa,
    const float* __restrict__ Wr0_at, const float* __restrict__ Wr0_ta,
    const float* __restrict__ bl0_tt, const float* __restrict__ bl0_aa,
    const float* __restrict__ bl0_at, const float* __restrict__ bl0_ta,
    const float* __restrict__ Wl1_tt, const float* __restrict__ Wl1_aa,
    const float* __restrict__ Wl1_at, const float* __restrict__ Wl1_ta,
    const float* __restrict__ Wr1_tt, const float* __restrict__ Wr1_aa,
    const float* __restrict__ Wr1_at, const float* __restrict__ Wr1_ta,
    const float* __restrict__ bl1_tt, const float* __restrict__ bl1_aa,
    const float* __restrict__ bl1_at, const float* __restrict__ bl1_ta,
    unsigned short* __restrict__ xb_tx, unsigned short* __restrict__ xb_ad,
    uint2* __restrict__ x8_tx, uint2* __restrict__ x8_ad,
    unsigned short* __restrict__ wb_tt, unsigned short* __restrict__ wb_aa,
    unsigned short* __restrict__ wb_at, unsigned short* __restrict__ wb_ta,
    unsigned short* __restrict__ wr0c_tx, unsigned short* __restrict__ wr0c_ad,
    float* __restrict__ b0c, unsigned short* __restrict__ wzb,
    float* __restrict__ b1c, int N)
{
    int i = blockIdx.x * blockDim.x + threadIdx.x;
    int nconv = N * DIN / 8;                 // 800000
    if (i < nconv) {
        {
            const float4* p = (const float4*)(x_tx + (size_t)i * 8);
            float4 a = p[0], b = p[1];
            uint4 o;
            o.x = (unsigned)f2bf(a.x) | ((unsigned)f2bf(a.y) << 16);
            o.y = (unsigned)f2bf(a.z) | ((unsigned)f2bf(a.w) << 16);
            o.z = (unsigned)f2bf(b.x) | ((unsigned)f2bf(b.y) << 16);
            o.w = (unsigned)f2bf(b.z) | ((unsigned)f2bf(b.w) << 16);
            *(uint4*)(xb_tx + (size_t)i * 8) = o;
            x8_tx[i] = make_uint2(pk_fp8(a), pk_fp8(b));
        }
        {
            const float4* p = (const float4*)(x_addr + (size_t)i * 8);
            float4 a = p[0], b = p[1];
            uint4 o;
            o.x = (unsigned)f2bf(a.x) | ((unsigned)f2bf(a.y) << 16);
            o.y = (unsigned)f2bf(a.z) | ((unsigned)f2bf(a.w) << 16);
            o.z = (unsigned)f2bf(b.x) | ((unsigned)f2bf(b.y) << 16);
            o.w = (unsigned)f2bf(b.z) | ((unsigned)f2bf(b.w) << 16);
            *(uint4*)(xb_ad + (size_t)i * 8) = o;
            x8_ad[i] = make_uint2(pk_fp8(a), pk_fp8(b));
        }
    }
    if (i < DH * DIN) {
        wb_tt[i] = f2bf(Wl0_tt[i]);
        wb_aa[i] = f2bf(Wl0_aa[i]);
        wb_at[i] = f2bf(Wl0_at[i]);
        wb_ta[i] = f2bf(Wl0_ta[i]);
        wr0c_tx[i] = f2bf(Wr0_tt[i] + Wr0_at[i]);
        wr0c_ad[i] = f2bf(Wr0_aa[i] + Wr0_ta[i]);
    }
    if (i < DH) {
        b0c[i]      = bl0_tt[i] + bl0_at[i];
        b0c[DH + i] = bl0_aa[i] + bl0_ta[i];
    }
    if (i < 2 * 16 * DH) {                    // wzb: [type][16][256] bf16, rows>=6 zero
        int type = i >> 12;
        int rem = i & 4095;
        int r = rem >> 8;
        int c = rem & 255;
        float v = 0.f;
        if (r < 6) {
            const float* A = type ? Wl1_aa : Wl1_tt;
            const float* B = type ? Wl1_at : Wl1_ta;
            if (r == 0) v = A[c];
            else if (r == 1) v = A[DH + c];
            else if (r == 2) v = B[c];
            else if (r == 3) v = B[DH + c];
            else if (r == 4) v = type ? (Wr1_aa[c] + Wr1_ta[c]) : (Wr1_tt[c] + Wr1_at[c]);
            else             v = type ? (Wr1_aa[DH + c] + Wr1_ta[DH + c])
                                      : (Wr1_tt[DH + c] + Wr1_at[DH + c]);
        }
        wzb[i] = f2bf(v);
    }
    if (i < 2) {
        b1c[i]     = bl1_tt[i] + bl1_at[i];
        b1c[2 + i] = bl1_aa[i] + bl1_ta[i];
    }
}

// ---------------- count: 8 edges/thread, independent atomic chains ----------
__global__ __launch_bounds__(256) void count_kernel(
    const int* __restrict__ e0, const int* __restrict__ e1,
    const int* __restrict__ e2, const int* __restrict__ e3,
    int* __restrict__ cnt, int* __restrict__ rank, int E, int N)
{
    int r = blockIdx.y;
    const int* e = (r == 0) ? e0 : (r == 1) ? e1 : (r == 2) ? e2 : e3;
    int base = (blockIdx.x * 256 + threadIdx.x) * 8;
    int* cb = cnt + r * N;
    int* rk = rank + (size_t)r * E;
    if (base + 8 <= E) {
        int4 d0 = *(const int4*)(e + E + base);
        int4 d1 = *(const int4*)(e + E + base + 4);
        int4 r0, r1;
        r0.x = atomicAdd(&cb[d0.x], 1);
        r0.y = atomicAdd(&cb[d0.y], 1);
        r0.z = atomicAdd(&cb[d0.z], 1);
        r0.w = atomicAdd(&cb[d0.w], 1);
        r1.x = atomicAdd(&cb[d1.x], 1);
        r1.y = atomicAdd(&cb[d1.y], 1);
        r1.z = atomicAdd(&cb[d1.z], 1);
        r1.w = atomicAdd(&cb[d1.w], 1);
        *(int4*)(rk + base) = r0;
        *(int4*)(rk + base + 4) = r1;
    } else {
        for (int i = base; i < E; ++i)
            rk[i] = atomicAdd(&cb[e[E + i]], 1);
    }
}

// single-kernel decoupled-lookback exclusive scan (ticket-ordered)
__global__ __launch_bounds__(1024) void scan_kernel(
    const int* __restrict__ cnt, int* __restrict__ excl,
    unsigned long long* __restrict__ desc, int n)
{
    __shared__ int sdata[1024];
    __shared__ int sseg;
    __shared__ int sprev;
    if (threadIdx.x == 0) sseg = (int)atomicAdd(&desc[256], 1ULL);
    __syncthreads();
    int seg = sseg;
    int i = seg * 1024 + threadIdx.x;
    int v = (i < n) ? cnt[i] : 0;
    sdata[threadIdx.x] = v;
    __syncthreads();
    for (int off = 1; off < 1024; off <<= 1) {
        int t = (threadIdx.x >= off) ? sdata[threadIdx.x - off] : 0;
        __syncthreads();
        sdata[threadIdx.x] += t;
        __syncthreads();
    }
    if (threadIdx.x == 0) {
        int total = sdata[1023];
        int prev = 0;
        if (seg == 0) {
            atomicExch(&desc[0], ((unsigned long long)(unsigned)total << 2) | 2ULL);
        } else {
            atomicExch(&desc[seg], ((unsigned long long)(unsigned)total << 2) | 1ULL);
            int j = seg - 1;
            for (;;) {
                unsigned long long d = atomicAdd(&desc[j], 0ULL);
                unsigned st = (unsigned)(d & 3ULL);
                if (st == 0u) continue;
                prev += (int)(d >> 2);
                if (st == 2u) break;
                --j;
            }
            atomicExch(&desc[seg],
                       ((unsigned long long)(unsigned)(prev + total) << 2) | 2ULL);
        }
        sprev = prev;
    }
    __syncthreads();
    if (i < n) excl[i] = sprev + sdata[threadIdx.x] - v;
}

// ---------------- fill: 4 edges/thread, no atomics ----------------
__global__ __launch_bounds__(256) void fill_kernel(
    const int* __restrict__ e0, const int* __restrict__ e1,
    const int* __restrict__ e2, const int* __restrict__ e3,
    const int* __restrict__ rowptr, const int* __restrict__ rank,
    int* __restrict__ col, int E, int N)
{
    int r = blockIdx.y;
    const int* e = (r == 0) ? e0 : (r == 1) ? e1 : (r == 2) ? e2 : e3;
    const int* rp = rowptr + r * N;
    const int* rk = rank + (size_t)r * E;
    int base = (blockIdx.x * 256 + threadIdx.x) * 4;
    if (base + 4 <= E) {
        int4 s = *(const int4*)(e + base);
        int4 d = *(const int4*)(e + E + base);
        int4 rr = *(const int4*)(rk + base);
        int p0 = rp[d.x], p1 = rp[d.y], p2 = rp[d.z], p3 = rp[d.w];
        col[p0 + rr.x] = s.x;
        col[p1 + rr.y] = s.y;
        col[p2 + rr.z] = s.z;
        col[p3 + rr.w] = s.w;
    } else {
        for (int i = base; i < E; ++i)
            col[rp[e[E + i]] + rk[i]] = e[i];
    }
}

// ---------------- layer-0 mean aggregation: fp8 rows, 8 lanes per task --------
// lane d of task-octet reads uint4 = 16 fp8 = dims [16d,16d+16). No cross-lane
// reduction; 8 tasks per wave; unroll-2 independent accumulation chains.
__global__ __launch_bounds__(256) void agg_kernel(
    const uint4* __restrict__ x8_tx, const uint4* __restrict__ x8_ad,
    const int* __restrict__ rowptr, const int* __restrict__ cnt,
    const int* __restrict__ col, unsigned short* __restrict__ aggb, int N)
{
    int r = blockIdx.y;                        // 0=tt 1=aa 2=at 3=ta
    const uint4* xs = (r == 0 || r == 3) ? x8_tx : x8_ad;
    int t = threadIdx.x;
    int wv = t >> 6;
    int l  = t & 63;
    int oct = l >> 3;                          // task within wave (0..7)
    int d   = l & 7;                           // 16-dim slot (0..7)
    int node = blockIdx.x * 32 + wv * 8 + oct;
    if (node >= N) return;
    int idx = r * N + node;
    int base = rowptr[idx];
    int c    = cnt[idx];
    const int* cl = col + base;
    float a0[16] = {}, a1[16] = {};
    int e = 0;
    for (; e + 2 <= c; e += 2) {
        int s0 = cl[e];
        int s1 = cl[e + 1];
        uint4 u0 = xs[((unsigned)s0 << 3) + d];
        uint4 u1 = xs[((unsigned)s1 << 3) + d];
        acc_fp8x16(a0, u0);
        acc_fp8x16(a1, u1);
    }
    if (e < c) {
        int s0 = cl[e];
        uint4 u0 = xs[((unsigned)s0 << 3) + d];
        acc_fp8x16(a0, u0);
    }
    float sc = 1.0f / fmaxf((float)c, 1.0f);
    uint4 o0, o1;
    o0.x = (unsigned)f2bf((a0[0] + a1[0]) * sc)  | ((unsigned)f2bf((a0[1] + a1[1]) * sc) << 16);
    o0.y = (unsigned)f2bf((a0[2] + a1[2]) * sc)  | ((unsigned)f2bf((a0[3] + a1[3]) * sc) << 16);
    o0.z = (unsigned)f2bf((a0[4] + a1[4]) * sc)  | ((unsigned)f2bf((a0[5] + a1[5]) * sc) << 16);
    o0.w = (unsigned)f2bf((a0[6] + a1[6]) * sc)  | ((unsigned)f2bf((a0[7] + a1[7]) * sc) << 16);
    o1.x = (unsigned)f2bf((a0[8] + a1[8]) * sc)  | ((unsigned)f2bf((a0[9] + a1[9]) * sc) << 16);
    o1.y = (unsigned)f2bf((a0[10] + a1[10]) * sc) | ((unsigned)f2bf((a0[11] + a1[11]) * sc) << 16);
    o1.z = (unsigned)f2bf((a0[12] + a1[12]) * sc) | ((unsigned)f2bf((a0[13] + a1[13]) * sc) << 16);
    o1.w = (unsigned)f2bf((a0[14] + a1[14]) * sc) | ((unsigned)f2bf((a0[15] + a1[15]) * sc) << 16);
    uint4* orow = (uint4*)(aggb + ((size_t)r * N + node) * DIN);   // 16 uint4/row
    orow[d * 2]     = o0;
    orow[d * 2 + 1] = o1;
}

// ---------------- gemm0 + fused layer-1 transform, LDS-staged A ----------------
__global__ __launch_bounds__(256) void gemm0z_kernel(
    const unsigned short* __restrict__ xb_tx, const unsigned short* __restrict__ xb_ad,
    const unsigned short* __restrict__ aggb,
    const unsigned short* __restrict__ wb_tt, const unsigned short* __restrict__ wb_at,
    const unsigned short* __restrict__ wr0c_tx,
    const unsigned short* __restrict__ wb_aa, const unsigned short* __restrict__ wb_ta,
    const unsigned short* __restrict__ wr0c_ad,
    const float* __restrict__ b0c, const unsigned short* __restrict__ wzb,
    const float* __restrict__ b1c,
    float* __restrict__ z, float* __restrict__ outp, int N)
{
    __shared__ unsigned short lds[3 * 64 * LDSA];   // 52224 B; h (64*LDSH) aliases it
    const int type = blockIdx.y;
    const unsigned short* xself = type ? xb_ad : xb_tx;
    const unsigned short* A0 = aggb + (size_t)(type ? 1 : 0) * N * DIN;  // aa / tt
    const unsigned short* A1 = aggb + (size_t)(type ? 3 : 2) * N * DIN;  // ta / at
    const unsigned short* W0 = type ? wb_aa   : wb_tt;
    const unsigned short* W1 = type ? wb_ta   : wb_at;
    const unsigned short* W2 = type ? wr0c_ad : wr0c_tx;
    const float* bias = b0c + type * DH;
    float* zA = type ? (z + (size_t)1 * N * 2) : z;                       // aa / tt
    float* zB = type ? (z + (size_t)2 * N * 2) : (z + (size_t)3 * N * 2); // at / ta
    float* outSelf = outp + (size_t)type * N * 2;

    const int t  = threadIdx.x;
    const int wv = t >> 6;
    const int l  = t & 63;
    const int q  = l >> 4;
    const int lr = l & 15;
    const int m0 = blockIdx.x * 64;
    const int n0 = wv * 64;

    // ---- phase 1: stage A tiles (3072 chunks of 16B; 12 per thread) ----
    {
        const uint4* As[3] = {(const uint4*)A0, (const uint4*)A1, (const uint4*)xself};
#pragma unroll
        for (int i = 0; i < 12; ++i) {
            int cid = i * 256 + t;
            int seg = cid >> 10;
            int rem = cid & 1023;
            int row = rem >> 4;
            int ch  = rem & 15;
            int gr = m0 + row; if (gr >= N) gr = N - 1;
            uint4 v = As[seg][((unsigned)gr << 4) + ch];
            *(uint4*)&lds[(seg * 64 + row) * LDSA + ch * 8] = v;
        }
    }
    __syncthreads();

    // ---- phase 2: K-loop ----
    f32x4 accm[4][4] = {};
    {
        const unsigned short* Ws[3] = {W0, W1, W2};
        for (int seg = 0; seg < 3; ++seg) {
            const unsigned short* W = Ws[seg];
            const unsigned short* la = &lds[(seg * 64 + lr) * LDSA + q * 8];
            const unsigned short* pb0 = W + (unsigned)(n0 + lr) * DIN + q * 8;
            const unsigned short* pb1 = W + (unsigned)(n0 + 16 + lr) * DIN + q * 8;
            const unsigned short* pb2 = W + (unsigned)(n0 + 32 + lr) * DIN + q * 8;
            const unsigned short* pb3 = W + (unsigned)(n0 + 48 + lr) * DIN + q * 8;
#pragma unroll
            for (int k = 0; k < DIN; k += 32) {
                bf16x8 b0 = *(const bf16x8*)(pb0 + k);
                bf16x8 b1 = *(const bf16x8*)(pb1 + k);
                bf16x8 b2 = *(const bf16x8*)(pb2 + k);
                bf16x8 b3 = *(const bf16x8*)(pb3 + k);
#pragma unroll
                for (int mt = 0; mt < 4; ++mt) {
                    bf16x8 a = *(const bf16x8*)(la + mt * 16 * LDSA + k);
                    accm[mt][0] = __builtin_amdgcn_mfma_f32_16x16x32_bf16(a, b0, accm[mt][0], 0, 0, 0);
                    accm[mt][1] = __builtin_amdgcn_mfma_f32_16x16x32_bf16(a, b1, accm[mt][1], 0, 0, 0);
                    accm[mt][2] = __builtin_amdgcn_mfma_f32_16x16x32_bf16(a, b2, accm[mt][2], 0, 0, 0);
                    accm[mt][3] = __builtin_amdgcn_mfma_f32_16x16x32_bf16(a, b3, accm[mt][3], 0, 0, 0);
                }
            }
        }
    }
    __syncthreads();   // all LDS-A reads done before h overwrites

    // ---- phase 3: h = relu(acc + bias) -> LDS bf16 ----
    {
        float bias_nt[4];
#pragma unroll
        for (int nt = 0; nt < 4; ++nt) bias_nt[nt] = bias[n0 + nt * 16 + lr];
#pragma unroll
        for (int mt = 0; mt < 4; ++mt) {
#pragma unroll
            for (int nt = 0; nt < 4; ++nt) {
                int colc = n0 + nt * 16 + lr;
#pragma unroll
                for (int rr = 0; rr < 4; ++rr) {
                    int row = mt * 16 + q * 4 + rr;
                    lds[row * LDSH + colc] =
                        f2bf(fmaxf(accm[mt][nt][rr] + bias_nt[nt], 0.f));
                }
            }
        }
    }
    __syncthreads();

    // ---- phase 4: z = h @ Wz^T (one 16-row m-tile per wave) ----
    {
        const unsigned short* wz = wzb + (size_t)type * 16 * DH;
        f32x4 az = {};
        const unsigned short* la = &lds[(wv * 16 + lr) * LDSH + q * 8];
        const unsigned short* pb = wz + lr * DH + q * 8;
#pragma unroll
        for (int k = 0; k < DH; k += 32) {
            bf16x8 a = *(const bf16x8*)(la + k);
            bf16x8 b = *(const bf16x8*)(pb + k);
            az = __builtin_amdgcn_mfma_f32_16x16x32_bf16(a, b, az, 0, 0, 0);
        }
        if (lr < 6) {
#pragma unroll
            for (int reg = 0; reg < 4; ++reg) {
                int node = m0 + wv * 16 + q * 4 + reg;
                if (node < N) {
                    float v = az[reg];
                    if (lr < 2)      zA[node * 2 + lr] = v;
                    else if (lr < 4) zB[node * 2 + lr - 2] = v;
                    else             outSelf[node * 2 + lr - 4] = v + b1c[type * 2 + lr - 4];
                }
            }
        }
    }
}

// ---------------- layer-1 aggregate (y=2): 8 lanes per node ----------------
__global__ __launch_bounds__(256) void l1_agg_kernel(
    const int* __restrict__ rowptr, const int* __restrict__ cnt, const int* __restrict__ col,
    const float* __restrict__ z, float* __restrict__ out, int N)
{
    const int type = blockIdx.y;
    const int rA = type ? 1 : 0;
    const int rB = type ? 3 : 2;
    const float* zAp = type ? (z + (size_t)1 * N * 2) : z;
    const float* zBp = type ? (z + (size_t)3 * N * 2) : (z + (size_t)2 * N * 2);
    float* outp = out + (size_t)type * N * 2;

    const int t = threadIdx.x;
    const int wave = t >> 6;
    const int l = t & 63;
    const int sub = l >> 3;       // node within wave's 8
    const int es  = l & 7;        // edge slot
    int node = blockIdx.x * 32 + wave * 8 + sub;
    bool valid = node < N;

    float ax = 0.f, ay = 0.f;
#pragma unroll
    for (int ri = 0; ri < 2; ++ri) {
        int rel = ri ? rB : rA;
        const float* zp = ri ? zBp : zAp;
        int b = 0, c = 0;
        if (valid) { b = rowptr[rel * N + node]; c = cnt[rel * N + node]; }
        const int* cl = col + b;
        float sx = 0.f, sy = 0.f;
        for (int e = es; e < c; e += 8) {
            int s = cl[e];
            float2 v = *(const float2*)(zp + (size_t)s * 2);
            sx += v.x; sy += v.y;
        }
        sx += __shfl_xor(sx, 1, 64); sy += __shfl_xor(sy, 1, 64);
        sx += __shfl_xor(sx, 2, 64); sy += __shfl_xor(sy, 2, 64);
        sx += __shfl_xor(sx, 4, 64); sy += __shfl_xor(sy, 4, 64);
        float sc = 1.0f / fmaxf((float)c, 1.0f);
        ax += sx * sc; ay += sy * sc;
    }
    if (valid && es == 0) {
        float2 o = *(float2*)(outp + (size_t)node * 2);   // self term from gemm0z
        o.x += ax; o.y += ay;
        *(float2*)(outp + (size_t)node * 2) = o;
    }
}

// ---------------- launch ----------------
extern "C" void kernel_launch(void* const* d_in, const int* in_sizes, int n_in,
                              void* d_out, int out_size, void* d_ws, size_t ws_size,
                              hipStream_t stream)
{
    const float* x_tx   = (const float*)d_in[0];
    const float* x_addr = (const float*)d_in[1];
    const int* e_tt = (const int*)d_in[2];
    const int* e_aa = (const int*)d_in[3];
    const int* e_at = (const int*)d_in[4];
    const int* e_ta = (const int*)d_in[5];
    const float* Wl0_tt = (const float*)d_in[6];
    const float* bl0_tt = (const float*)d_in[7];
    const float* Wr0_tt = (const float*)d_in[8];
    const float* Wl0_aa = (const float*)d_in[9];
    const float* bl0_aa = (const float*)d_in[10];
    const float* Wr0_aa = (const float*)d_in[11];
    const float* Wl0_at = (const float*)d_in[12];
    const float* bl0_at = (const float*)d_in[13];
    const float* Wr0_at = (const float*)d_in[14];
    const float* Wl0_ta = (const float*)d_in[15];
    const float* bl0_ta = (const float*)d_in[16];
    const float* Wr0_ta = (const float*)d_in[17];
    const float* Wl1_tt = (const float*)d_in[18];
    const float* bl1_tt = (const float*)d_in[19];
    const float* Wr1_tt = (const float*)d_in[20];
    const float* Wl1_aa = (const float*)d_in[21];
    const float* bl1_aa = (const float*)d_in[22];
    const float* Wr1_aa = (const float*)d_in[23];
    const float* Wl1_at = (const float*)d_in[24];
    const float* bl1_at = (const float*)d_in[25];
    const float* Wr1_at = (const float*)d_in[26];
    const float* Wl1_ta = (const float*)d_in[27];
    const float* bl1_ta = (const float*)d_in[28];
    const float* Wr1_ta = (const float*)d_in[29];

    const int N = in_sizes[0] / DIN;   // 50000
    const int E = in_sizes[2] / 2;     // 400000

    size_t off = 0;
    char* base = (char*)d_ws;
    auto alloc = [&](size_t bytes) -> void* {
        void* p = base + off;
        off += (bytes + 255) & ~(size_t)255;
        return p;
    };
    int*   cnt    = (int*)  alloc((size_t)4 * N * 4);        // zeroed by memset
    unsigned long long* desc = (unsigned long long*)alloc(257 * 8);  // contiguous w/ cnt
    int*   rowptr = (int*)  alloc((size_t)4 * N * 4);
    int*   rank   = (int*)  alloc((size_t)4 * E * 4);
    int*   col    = (int*)  alloc((size_t)4 * E * 4);
    unsigned short* xb_tx = (unsigned short*)alloc((size_t)N * DIN * 2);
    unsigned short* xb_ad = (unsigned short*)alloc((size_t)N * DIN * 2);
    uint2* x8_tx = (uint2*)alloc((size_t)N * DIN);
    uint2* x8_ad = (uint2*)alloc((size_t)N * DIN);
    unsigned short* aggb  = (unsigned short*)alloc((size_t)4 * N * DIN * 2);
    float* z      = (float*)alloc((size_t)4 * N * 2 * 4);
    unsigned short* wb_tt  = (unsigned short*)alloc((size_t)DH * DIN * 2);
    unsigned short* wb_aa  = (unsigned short*)alloc((size_t)DH * DIN * 2);
    unsigned short* wb_at  = (unsigned short*)alloc((size_t)DH * DIN * 2);
    unsigned short* wb_ta  = (unsigned short*)alloc((size_t)DH * DIN * 2);
    unsigned short* wr0c_tx = (unsigned short*)alloc((size_t)DH * DIN * 2);
    unsigned short* wr0c_ad = (unsigned short*)alloc((size_t)DH * DIN * 2);
    float* b0c    = (float*)alloc((size_t)2 * DH * 4);
    unsigned short* wzb = (unsigned short*)alloc((size_t)2 * 16 * DH * 2);
    float* b1c    = (float*)alloc((size_t)2 * 2 * 4);
    (void)ws_size;

    float* outp = (float*)d_out;
    const int n4 = 4 * N;

    // 0. zero cnt + desc (contiguous in ws)
    hipMemsetAsync(cnt, 0, (((size_t)4 * N * 4 + 255) & ~(size_t)255) + 257 * 8, stream);

    // 1. setup
    {
        int nconv = N * DIN / 8;
        setup_kernel<<<(nconv + 255) / 256, 256, 0, stream>>>(
            x_tx, x_addr,
            Wl0_tt, Wl0_aa, Wl0_at, Wl0_ta,
            Wr0_tt, Wr0_aa, Wr0_at, Wr0_ta,
            bl0_tt, bl0_aa, bl0_at, bl0_ta,
            Wl1_tt, Wl1_aa, Wl1_at, Wl1_ta,
            Wr1_tt, Wr1_aa, Wr1_at, Wr1_ta,
            bl1_tt, bl1_aa, bl1_at, bl1_ta,
            xb_tx, xb_ad, x8_tx, x8_ad,
            wb_tt, wb_aa, wb_at, wb_ta, wr0c_tx, wr0c_ad,
            b0c, wzb, b1c, N);
    }
    // 2. counts + ranks (8 edges/thread)
    {
        dim3 g((E + 2047) / 2048, 4);
        count_kernel<<<g, 256, 0, stream>>>(e_tt, e_aa, e_at, e_ta, cnt, rank, E, N);
    }
    // 3. scan
    {
        int nb = (n4 + 1023) / 1024;
        scan_kernel<<<nb, 1024, 0, stream>>>(cnt, rowptr, desc, n4);
    }
    // 4. fill (4 edges/thread, no atomics)
    {
        dim3 g((E + 1023) / 1024, 4);
        fill_kernel<<<g, 256, 0, stream>>>(e_tt, e_aa, e_at, e_ta, rowptr, rank, col, E, N);
    }
    // 5. aggregation (fp8 gather, 8 lanes/task)
    {
        dim3 g((N + 31) / 32, 4);
        agg_kernel<<<g, 256, 0, stream>>>((const uint4*)x8_tx, (const uint4*)x8_ad,
                                          rowptr, cnt, col, aggb, N);
    }
    // 6. gemm0 + fused layer-1 transform
    {
        dim3 g((N + 63) / 64, 2);
        gemm0z_kernel<<<g, 256, 0, stream>>>(
            xb_tx, xb_ad, aggb,
            wb_tt, wb_at, wr0c_tx, wb_aa, wb_ta, wr0c_ad,
            b0c, wzb, b1c, z, outp, N);
    }
    // 7. layer-1 aggregation
    {
        dim3 g((N + 31) / 32, 2);
        l1_agg_kernel<<<g, 256, 0, stream>>>(rowptr, cnt, col, z, outp, N);
    }
}

// Round 9
// 303.230 us; speedup vs baseline: 1.3541x; 1.2376x over previous
//
#include <hip/hip_runtime.h>
#include <hip/hip_fp8.h>

// HeteroSAGE on MI355X — round 9: atomic-free-ish CSR build via two-level
// bucket sort (coarse dst>>8 partition, then per-bucket fine grouping).
// Replaces count(1.6M device atomics @ ~10/cyc wall) + scan + random-scatter
// fill with 4 streaming kernels and ~180K atomics.
//
// Pipeline (memset + 8 dispatches):
//   0. memsetAsync: bcnt (4*nb ints) -> 0
//   1. setup: x->bf16 + x->fp8, fold weights, build Wz bf16
//   2. K1 bhist (y=4): LDS 196-bin histo per block -> global atomicAdd per bin
//   3. K2 bscan: one block, scan 784 bucket counts -> bbase/bcur (global pos)
//   4. K3 bscatter (y=4): reserve per-bucket ranges (1 atomic/block/bin),
//      scatter packed (fine<<16|src) u32 to tmp (bucket-run coalesced)
//   5. K4 bgroup (nb x 4): per-bucket LDS histo + scan -> rowptr/cnt direct,
//      grouped col writes (coalesced)
//   6. agg (y=4): fp8 rows, 8 lanes/(node,rel) task -> aggb bf16
//   7. gemm0z (y=2): LDS-staged A, MFMA; h->LDS bf16; z via MFMA
//   8. l1_agg (y=2): 8 lanes/node CSR walk, xor-reduce, out += mean(z)

#define DIN 128
#define DH  256
#define LDSA 136    // A-tile row stride (shorts): 128+8 pad
#define LDSH 264    // h-tile row stride (shorts): 256+8 pad

typedef __attribute__((ext_vector_type(8))) short bf16x8;
typedef __attribute__((ext_vector_type(4))) float f32x4;
typedef __attribute__((ext_vector_type(2))) float f32x2;

__device__ __forceinline__ unsigned short f2bf(float f) {
    unsigned int u = __float_as_uint(f);
    u = (u + 0x7fffu + ((u >> 16) & 1u)) >> 16;   // RNE
    return (unsigned short)u;
}

#if __has_builtin(__builtin_amdgcn_cvt_pk_fp8_f32) && __has_builtin(__builtin_amdgcn_cvt_pk_f32_fp8)
__device__ __forceinline__ unsigned pk_fp8(float4 a) {
    unsigned v = (unsigned)__builtin_amdgcn_cvt_pk_fp8_f32(a.x, a.y, 0, false);
    v = (unsigned)__builtin_amdgcn_cvt_pk_fp8_f32(a.z, a.w, (int)v, true);
    return v;
}
__device__ __forceinline__ void acc_fp8x4(float* a, unsigned u) {
    f32x2 f0 = __builtin_amdgcn_cvt_pk_f32_fp8((int)u, false);
    f32x2 f1 = __builtin_amdgcn_cvt_pk_f32_fp8((int)u, true);
    a[0] += f0.x; a[1] += f0.y; a[2] += f1.x; a[3] += f1.y;
}
#else
__device__ __forceinline__ unsigned pk_fp8(float4 a) {
    __hip_fp8_e4m3 v0(a.x), v1(a.y), v2(a.z), v3(a.w);
    return (unsigned)v0.__x | ((unsigned)v1.__x << 8) |
           ((unsigned)v2.__x << 16) | ((unsigned)v3.__x << 24);
}
__device__ __forceinline__ void acc_fp8x4(float* a, unsigned u) {
    __hip_fp8_e4m3 v0, v1, v2, v3;
    v0.__x = (unsigned char)(u & 0xff);
    v1.__x = (unsigned char)((u >> 8) & 0xff);
    v2.__x = (unsigned char)((u >> 16) & 0xff);
    v3.__x = (unsigned char)((u >> 24) & 0xff);
    a[0] += (float)v0; a[1] += (float)v1; a[2] += (float)v2; a[3] += (float)v3;
}
#endif

__device__ __forceinline__ void acc_fp8x16(float* a, uint4 u) {
    acc_fp8x4(a + 0,  u.x);
    acc_fp8x4(a + 4,  u.y);
    acc_fp8x4(a + 8,  u.z);
    acc_fp8x4(a + 12, u.w);
}

// ---------------- setup ----------------
__global__ __launch_bounds__(256) void setup_kernel(
    const float* __restrict__ x_tx, const float* __restrict__ x_addr,
    const float* __restrict__ Wl0_tt, const float* __restrict__ Wl0_aa,
    const float* __restrict__ Wl0_at, const float* __restrict__ Wl0_ta,
    const float* __restrict__ Wr0_tt, const float* __restrict__ Wr0_aa,
    const float* __restrict__ Wr0_at, const float* __restrict__ Wr0_ta,
    const float* __restrict__ bl0_tt, const float* __restrict__ bl0_aa,
    const float* __restrict__ bl0_at, const float* __restrict__ bl0_ta,
    const float* __restrict__ Wl1_tt, const float* __restrict__ Wl1_aa,
    const float* __restrict__ Wl1_at, const float* __restrict__ Wl1_ta,
    const float* __restrict__ Wr1_tt, const float* __restrict__ Wr1_aa,
    const float* __restrict__ Wr1_at, const float* __restrict__ Wr1_ta,
    const float* __restrict__ bl1_tt, const float* __restrict__ bl1_aa,
    const float* __restrict__ bl1_at, const float* __restrict__ bl1_ta,
    unsigned short* __restrict__ xb_tx, unsigned short* __restrict__ xb_ad,
    uint2* __restrict__ x8_tx, uint2* __restrict__ x8_ad,
    unsigned short* __restrict__ wb_tt, unsigned short* __restrict__ wb_aa,
    unsigned short* __restrict__ wb_at, unsigned short* __restrict__ wb_ta,
    unsigned short* __restrict__ wr0c_tx, unsigned short* __restrict__ wr0c_ad,
    float* __restrict__ b0c, unsigned short* __restrict__ wzb,
    float* __restrict__ b1c, int N)
{
    int i = blockIdx.x * blockDim.x + threadIdx.x;
    int nconv = N * DIN / 8;                 // 800000
    if (i < nconv) {
        {
            const float4* p = (const float4*)(x_tx + (size_t)i * 8);
            float4 a = p[0], b = p[1];
            uint4 o;
            o.x = (unsigned)f2bf(a.x) | ((unsigned)f2bf(a.y) << 16);
            o.y = (unsigned)f2bf(a.z) | ((unsigned)f2bf(a.w) << 16);
            o.z = (unsigned)f2bf(b.x) | ((unsigned)f2bf(b.y) << 16);
            o.w = (unsigned)f2bf(b.z) | ((unsigned)f2bf(b.w) << 16);
            *(uint4*)(xb_tx + (size_t)i * 8) = o;
            x8_tx[i] = make_uint2(pk_fp8(a), pk_fp8(b));
        }
        {
            const float4* p = (const float4*)(x_addr + (size_t)i * 8);
            float4 a = p[0], b = p[1];
            uint4 o;
            o.x = (unsigned)f2bf(a.x) | ((unsigned)f2bf(a.y) << 16);
            o.y = (unsigned)f2bf(a.z) | ((unsigned)f2bf(a.w) << 16);
            o.z = (unsigned)f2bf(b.x) | ((unsigned)f2bf(b.y) << 16);
            o.w = (unsigned)f2bf(b.z) | ((unsigned)f2bf(b.w) << 16);
            *(uint4*)(xb_ad + (size_t)i * 8) = o;
            x8_ad[i] = make_uint2(pk_fp8(a), pk_fp8(b));
        }
    }
    if (i < DH * DIN) {
        wb_tt[i] = f2bf(Wl0_tt[i]);
        wb_aa[i] = f2bf(Wl0_aa[i]);
        wb_at[i] = f2bf(Wl0_at[i]);
        wb_ta[i] = f2bf(Wl0_ta[i]);
        wr0c_tx[i] = f2bf(Wr0_tt[i] + Wr0_at[i]);
        wr0c_ad[i] = f2bf(Wr0_aa[i] + Wr0_ta[i]);
    }
    if (i < DH) {
        b0c[i]      = bl0_tt[i] + bl0_at[i];
        b0c[DH + i] = bl0_aa[i] + bl0_ta[i];
    }
    if (i < 2 * 16 * DH) {                    // wzb: [type][16][256] bf16, rows>=6 zero
        int type = i >> 12;
        int rem = i & 4095;
        int r = rem >> 8;
        int c = rem & 255;
        float v = 0.f;
        if (r < 6) {
            const float* A = type ? Wl1_aa : Wl1_tt;
            const float* B = type ? Wl1_at : Wl1_ta;
            if (r == 0) v = A[c];
            else if (r == 1) v = A[DH + c];
            else if (r == 2) v = B[c];
            else if (r == 3) v = B[DH + c];
            else if (r == 4) v = type ? (Wr1_aa[c] + Wr1_ta[c]) : (Wr1_tt[c] + Wr1_at[c]);
            else             v = type ? (Wr1_aa[DH + c] + Wr1_ta[DH + c])
                                      : (Wr1_tt[DH + c] + Wr1_at[DH + c]);
        }
        wzb[i] = f2bf(v);
    }
    if (i < 2) {
        b1c[i]     = bl1_tt[i] + bl1_at[i];
        b1c[2 + i] = bl1_aa[i] + bl1_ta[i];
    }
}

// ---------------- K1: coarse bucket histogram (block-aggregated) ----------------
__global__ __launch_bounds__(256) void bhist_kernel(
    const int* __restrict__ e0, const int* __restrict__ e1,
    const int* __restrict__ e2, const int* __restrict__ e3,
    int* __restrict__ bcnt, int E, int nb)
{
    int r = blockIdx.y;
    const int* e = (r == 0) ? e0 : (r == 1) ? e1 : (r == 2) ? e2 : e3;
    __shared__ int h[256];
    if (threadIdx.x < nb) h[threadIdx.x] = 0;
    __syncthreads();
    int base = (blockIdx.x * 256 + threadIdx.x) * 16;
    if (base + 16 <= E) {
        const int4* p = (const int4*)(e + E + base);
        int4 d0 = p[0], d1 = p[1], d2 = p[2], d3 = p[3];
        atomicAdd(&h[(unsigned)d0.x >> 8], 1); atomicAdd(&h[(unsigned)d0.y >> 8], 1);
        atomicAdd(&h[(unsigned)d0.z >> 8], 1); atomicAdd(&h[(unsigned)d0.w >> 8], 1);
        atomicAdd(&h[(unsigned)d1.x >> 8], 1); atomicAdd(&h[(unsigned)d1.y >> 8], 1);
        atomicAdd(&h[(unsigned)d1.z >> 8], 1); atomicAdd(&h[(unsigned)d1.w >> 8], 1);
        atomicAdd(&h[(unsigned)d2.x >> 8], 1); atomicAdd(&h[(unsigned)d2.y >> 8], 1);
        atomicAdd(&h[(unsigned)d2.z >> 8], 1); atomicAdd(&h[(unsigned)d2.w >> 8], 1);
        atomicAdd(&h[(unsigned)d3.x >> 8], 1); atomicAdd(&h[(unsigned)d3.y >> 8], 1);
        atomicAdd(&h[(unsigned)d3.z >> 8], 1); atomicAdd(&h[(unsigned)d3.w >> 8], 1);
    } else {
        for (int i = base; i < E; ++i)
            atomicAdd(&h[(unsigned)e[E + i] >> 8], 1);
    }
    __syncthreads();
    if (threadIdx.x < nb) {
        int v = h[threadIdx.x];
        if (v) atomicAdd(&bcnt[r * nb + threadIdx.x], v);
    }
}

// ---------------- K2: scan bucket counts -> global bases & cursors ------------
__global__ __launch_bounds__(1024) void bscan_kernel(
    const int* __restrict__ bcnt, int* __restrict__ bbase, int* __restrict__ bcur, int n)
{
    __shared__ int s[1024];
    int t = threadIdx.x;
    int v = (t < n) ? bcnt[t] : 0;
    s[t] = v;
    __syncthreads();
    for (int off = 1; off < 1024; off <<= 1) {
        int x = (t >= off) ? s[t - off] : 0;
        __syncthreads();
        s[t] += x;
        __syncthreads();
    }
    if (t < n) {
        int ex = s[t] - v;
        bbase[t] = ex;
        bcur[t] = ex;
    }
    if (t == 0) bbase[n] = s[1023];   // total = 4E
}

// ---------------- K3: scatter to coarse buckets (packed fine<<16|src) ---------
__global__ __launch_bounds__(256) void bscatter_kernel(
    const int* __restrict__ e0, const int* __restrict__ e1,
    const int* __restrict__ e2, const int* __restrict__ e3,
    int* __restrict__ bcur, unsigned* __restrict__ tmp, int E, int nb)
{
    int r = blockIdx.y;
    const int* e = (r == 0) ? e0 : (r == 1) ? e1 : (r == 2) ? e2 : e3;
    __shared__ int h[256];
    __shared__ int lbase[256];
    __shared__ int lcur[256];
    if (threadIdx.x < nb) { h[threadIdx.x] = 0; lcur[threadIdx.x] = 0; }
    __syncthreads();
    int base = (blockIdx.x * 256 + threadIdx.x) * 16;
    int dst[16], src[16];
    int cnt16 = 0;
    if (base + 16 <= E) {
        const int4* pd = (const int4*)(e + E + base);
        const int4* ps = (const int4*)(e + base);
#pragma unroll
        for (int j = 0; j < 4; ++j) {
            int4 d = pd[j], s4 = ps[j];
            dst[j * 4 + 0] = d.x; dst[j * 4 + 1] = d.y; dst[j * 4 + 2] = d.z; dst[j * 4 + 3] = d.w;
            src[j * 4 + 0] = s4.x; src[j * 4 + 1] = s4.y; src[j * 4 + 2] = s4.z; src[j * 4 + 3] = s4.w;
        }
        cnt16 = 16;
    } else {
        for (int i = base; i < E; ++i) {
            dst[cnt16] = e[E + i];
            src[cnt16] = e[i];
            ++cnt16;
        }
    }
    for (int j = 0; j < cnt16; ++j)
        atomicAdd(&h[(unsigned)dst[j] >> 8], 1);
    __syncthreads();
    if (threadIdx.x < nb) {
        int c = h[threadIdx.x];
        if (c) lbase[threadIdx.x] = atomicAdd(&bcur[r * nb + threadIdx.x], c);
    }
    __syncthreads();
    for (int j = 0; j < cnt16; ++j) {
        int bk = (unsigned)dst[j] >> 8;
        int rank = atomicAdd(&lcur[bk], 1);
        tmp[lbase[bk] + rank] =
            (((unsigned)dst[j] & 255u) << 16) | (unsigned)src[j];
    }
}

// ---------------- K4: per-bucket fine grouping -> col, rowptr, cnt ------------
__global__ __launch_bounds__(256) void bgroup_kernel(
    const unsigned* __restrict__ tmp, const int* __restrict__ bbase,
    int* __restrict__ col, int* __restrict__ rowptr, int* __restrict__ cnt,
    int N, int nb)
{
    int b = blockIdx.x;     // bucket
    int r = blockIdx.y;     // relation
    int idx = r * nb + b;
    int lo = bbase[idx], hi = bbase[idx + 1];
    __shared__ int h[256];
    __shared__ int cur[256];
    __shared__ int exs[256];
    int t = threadIdx.x;
    h[t] = 0; cur[t] = 0;
    __syncthreads();
    for (int i = lo + t; i < hi; i += 256)
        atomicAdd(&h[(tmp[i] >> 16) & 255u], 1);
    __syncthreads();
    // exclusive scan of h
    {
        __shared__ int s[256];
        int v = h[t];
        s[t] = v;
        __syncthreads();
        for (int off = 1; off < 256; off <<= 1) {
            int x = (t >= off) ? s[t - off] : 0;
            __syncthreads();
            s[t] += x;
            __syncthreads();
        }
        exs[t] = s[t] - v;
    }
    __syncthreads();
    int d = b * 256 + t;
    if (d < N) {
        rowptr[r * N + d] = lo + exs[t];
        cnt[r * N + d] = h[t];
    }
    for (int i = lo + t; i < hi; i += 256) {
        unsigned p = tmp[i];
        int fine = (p >> 16) & 255u;
        int rank = atomicAdd(&cur[fine], 1);
        col[lo + exs[fine] + rank] = (int)(p & 0xffffu);
    }
}

// ---------------- layer-0 mean aggregation: fp8 rows, 8 lanes per task --------
__global__ __launch_bounds__(256) void agg_kernel(
    const uint4* __restrict__ x8_tx, const uint4* __restrict__ x8_ad,
    const int* __restrict__ rowptr, const int* __restrict__ cnt,
    const int* __restrict__ col, unsigned short* __restrict__ aggb, int N)
{
    int r = blockIdx.y;                        // 0=tt 1=aa 2=at 3=ta
    const uint4* xs = (r == 0 || r == 3) ? x8_tx : x8_ad;
    int t = threadIdx.x;
    int wv = t >> 6;
    int l  = t & 63;
    int oct = l >> 3;                          // task within wave (0..7)
    int d   = l & 7;                           // 16-dim slot (0..7)
    int node = blockIdx.x * 32 + wv * 8 + oct;
    if (node >= N) return;
    int idx = r * N + node;
    int base = rowptr[idx];
    int c    = cnt[idx];
    const int* cl = col + base;
    float a0[16] = {}, a1[16] = {};
    int e = 0;
    for (; e + 2 <= c; e += 2) {
        int s0 = cl[e];
        int s1 = cl[e + 1];
        uint4 u0 = xs[((unsigned)s0 << 3) + d];
        uint4 u1 = xs[((unsigned)s1 << 3) + d];
        acc_fp8x16(a0, u0);
        acc_fp8x16(a1, u1);
    }
    if (e < c) {
        int s0 = cl[e];
        uint4 u0 = xs[((unsigned)s0 << 3) + d];
        acc_fp8x16(a0, u0);
    }
    float sc = 1.0f / fmaxf((float)c, 1.0f);
    uint4 o0, o1;
    o0.x = (unsigned)f2bf((a0[0] + a1[0]) * sc)  | ((unsigned)f2bf((a0[1] + a1[1]) * sc) << 16);
    o0.y = (unsigned)f2bf((a0[2] + a1[2]) * sc)  | ((unsigned)f2bf((a0[3] + a1[3]) * sc) << 16);
    o0.z = (unsigned)f2bf((a0[4] + a1[4]) * sc)  | ((unsigned)f2bf((a0[5] + a1[5]) * sc) << 16);
    o0.w = (unsigned)f2bf((a0[6] + a1[6]) * sc)  | ((unsigned)f2bf((a0[7] + a1[7]) * sc) << 16);
    o1.x = (unsigned)f2bf((a0[8] + a1[8]) * sc)  | ((unsigned)f2bf((a0[9] + a1[9]) * sc) << 16);
    o1.y = (unsigned)f2bf((a0[10] + a1[10]) * sc) | ((unsigned)f2bf((a0[11] + a1[11]) * sc) << 16);
    o1.z = (unsigned)f2bf((a0[12] + a1[12]) * sc) | ((unsigned)f2bf((a0[13] + a1[13]) * sc) << 16);
    o1.w = (unsigned)f2bf((a0[14] + a1[14]) * sc) | ((unsigned)f2bf((a0[15] + a1[15]) * sc) << 16);
    uint4* orow = (uint4*)(aggb + ((size_t)r * N + node) * DIN);   // 16 uint4/row
    orow[d * 2]     = o0;
    orow[d * 2 + 1] = o1;
}

// ---------------- gemm0 + fused layer-1 transform, LDS-staged A ----------------
__global__ __launch_bounds__(256) void gemm0z_kernel(
    const unsigned short* __restrict__ xb_tx, const unsigned short* __restrict__ xb_ad,
    const unsigned short* __restrict__ aggb,
    const unsigned short* __restrict__ wb_tt, const unsigned short* __restrict__ wb_at,
    const unsigned short* __restrict__ wr0c_tx,
    const unsigned short* __restrict__ wb_aa, const unsigned short* __restrict__ wb_ta,
    const unsigned short* __restrict__ wr0c_ad,
    const float* __restrict__ b0c, const unsigned short* __restrict__ wzb,
    const float* __restrict__ b1c,
    float* __restrict__ z, float* __restrict__ outp, int N)
{
    __shared__ unsigned short lds[3 * 64 * LDSA];   // 52224 B; h (64*LDSH) aliases it
    const int type = blockIdx.y;
    const unsigned short* xself = type ? xb_ad : xb_tx;
    const unsigned short* A0 = aggb + (size_t)(type ? 1 : 0) * N * DIN;  // aa / tt
    const unsigned short* A1 = aggb + (size_t)(type ? 3 : 2) * N * DIN;  // ta / at
    const unsigned short* W0 = type ? wb_aa   : wb_tt;
    const unsigned short* W1 = type ? wb_ta   : wb_at;
    const unsigned short* W2 = type ? wr0c_ad : wr0c_tx;
    const float* bias = b0c + type * DH;
    float* zA = type ? (z + (size_t)1 * N * 2) : z;                       // aa / tt
    float* zB = type ? (z + (size_t)2 * N * 2) : (z + (size_t)3 * N * 2); // at / ta
    float* outSelf = outp + (size_t)type * N * 2;

    const int t  = threadIdx.x;
    const int wv = t >> 6;
    const int l  = t & 63;
    const int q  = l >> 4;
    const int lr = l & 15;
    const int m0 = blockIdx.x * 64;
    const int n0 = wv * 64;

    // ---- phase 1: stage A tiles (3072 chunks of 16B; 12 per thread) ----
    {
        const uint4* As[3] = {(const uint4*)A0, (const uint4*)A1, (const uint4*)xself};
#pragma unroll
        for (int i = 0; i < 12; ++i) {
            int cid = i * 256 + t;
            int seg = cid >> 10;
            int rem = cid & 1023;
            int row = rem >> 4;
            int ch  = rem & 15;
            int gr = m0 + row; if (gr >= N) gr = N - 1;
            uint4 v = As[seg][((unsigned)gr << 4) + ch];
            *(uint4*)&lds[(seg * 64 + row) * LDSA + ch * 8] = v;
        }
    }
    __syncthreads();

    // ---- phase 2: K-loop ----
    f32x4 accm[4][4] = {};
    {
        const unsigned short* Ws[3] = {W0, W1, W2};
        for (int seg = 0; seg < 3; ++seg) {
            const unsigned short* W = Ws[seg];
            const unsigned short* la = &lds[(seg * 64 + lr) * LDSA + q * 8];
            const unsigned short* pb0 = W + (unsigned)(n0 + lr) * DIN + q * 8;
            const unsigned short* pb1 = W + (unsigned)(n0 + 16 + lr) * DIN + q * 8;
            const unsigned short* pb2 = W + (unsigned)(n0 + 32 + lr) * DIN + q * 8;
            const unsigned short* pb3 = W + (unsigned)(n0 + 48 + lr) * DIN + q * 8;
#pragma unroll
            for (int k = 0; k < DIN; k += 32) {
                bf16x8 b0 = *(const bf16x8*)(pb0 + k);
                bf16x8 b1 = *(const bf16x8*)(pb1 + k);
                bf16x8 b2 = *(const bf16x8*)(pb2 + k);
                bf16x8 b3 = *(const bf16x8*)(pb3 + k);
#pragma unroll
                for (int mt = 0; mt < 4; ++mt) {
                    bf16x8 a = *(const bf16x8*)(la + mt * 16 * LDSA + k);
                    accm[mt][0] = __builtin_amdgcn_mfma_f32_16x16x32_bf16(a, b0, accm[mt][0], 0, 0, 0);
                    accm[mt][1] = __builtin_amdgcn_mfma_f32_16x16x32_bf16(a, b1, accm[mt][1], 0, 0, 0);
                    accm[mt][2] = __builtin_amdgcn_mfma_f32_16x16x32_bf16(a, b2, accm[mt][2], 0, 0, 0);
                    accm[mt][3] = __builtin_amdgcn_mfma_f32_16x16x32_bf16(a, b3, accm[mt][3], 0, 0, 0);
                }
            }
        }
    }
    __syncthreads();   // all LDS-A reads done before h overwrites

    // ---- phase 3: h = relu(acc + bias) -> LDS bf16 ----
    {
        float bias_nt[4];
#pragma unroll
        for (int nt = 0; nt < 4; ++nt) bias_nt[nt] = bias[n0 + nt * 16 + lr];
#pragma unroll
        for (int mt = 0; mt < 4; ++mt) {
#pragma unroll
            for (int nt = 0; nt < 4; ++nt) {
                int colc = n0 + nt * 16 + lr;
#pragma unroll
                for (int rr = 0; rr < 4; ++rr) {
                    int row = mt * 16 + q * 4 + rr;
                    lds[row * LDSH + colc] =
                        f2bf(fmaxf(accm[mt][nt][rr] + bias_nt[nt], 0.f));
                }
            }
        }
    }
    __syncthreads();

    // ---- phase 4: z = h @ Wz^T (one 16-row m-tile per wave) ----
    {
        const unsigned short* wz = wzb + (size_t)type * 16 * DH;
        f32x4 az = {};
        const unsigned short* la = &lds[(wv * 16 + lr) * LDSH + q * 8];
        const unsigned short* pb = wz + lr * DH + q * 8;
#pragma unroll
        for (int k = 0; k < DH; k += 32) {
            bf16x8 a = *(const bf16x8*)(la + k);
            bf16x8 b = *(const bf16x8*)(pb + k);
            az = __builtin_amdgcn_mfma_f32_16x16x32_bf16(a, b, az, 0, 0, 0);
        }
        if (lr < 6) {
#pragma unroll
            for (int reg = 0; reg < 4; ++reg) {
                int node = m0 + wv * 16 + q * 4 + reg;
                if (node < N) {
                    float v = az[reg];
                    if (lr < 2)      zA[node * 2 + lr] = v;
                    else if (lr < 4) zB[node * 2 + lr - 2] = v;
                    else             outSelf[node * 2 + lr - 4] = v + b1c[type * 2 + lr - 4];
                }
            }
        }
    }
}

// ---------------- layer-1 aggregate (y=2): 8 lanes per node ----------------
__global__ __launch_bounds__(256) void l1_agg_kernel(
    const int* __restrict__ rowptr, const int* __restrict__ cnt, const int* __restrict__ col,
    const float* __restrict__ z, float* __restrict__ out, int N)
{
    const int type = blockIdx.y;
    const int rA = type ? 1 : 0;
    const int rB = type ? 3 : 2;
    const float* zAp = type ? (z + (size_t)1 * N * 2) : z;
    const float* zBp = type ? (z + (size_t)3 * N * 2) : (z + (size_t)2 * N * 2);
    float* outp = out + (size_t)type * N * 2;

    const int t = threadIdx.x;
    const int wave = t >> 6;
    const int l = t & 63;
    const int sub = l >> 3;       // node within wave's 8
    const int es  = l & 7;        // edge slot
    int node = blockIdx.x * 32 + wave * 8 + sub;
    bool valid = node < N;

    float ax = 0.f, ay = 0.f;
#pragma unroll
    for (int ri = 0; ri < 2; ++ri) {
        int rel = ri ? rB : rA;
        const float* zp = ri ? zBp : zAp;
        int b = 0, c = 0;
        if (valid) { b = rowptr[rel * N + node]; c = cnt[rel * N + node]; }
        const int* cl = col + b;
        float sx = 0.f, sy = 0.f;
        for (int e = es; e < c; e += 8) {
            int s = cl[e];
            float2 v = *(const float2*)(zp + (size_t)s * 2);
            sx += v.x; sy += v.y;
        }
        sx += __shfl_xor(sx, 1, 64); sy += __shfl_xor(sy, 1, 64);
        sx += __shfl_xor(sx, 2, 64); sy += __shfl_xor(sy, 2, 64);
        sx += __shfl_xor(sx, 4, 64); sy += __shfl_xor(sy, 4, 64);
        float sc = 1.0f / fmaxf((float)c, 1.0f);
        ax += sx * sc; ay += sy * sc;
    }
    if (valid && es == 0) {
        float2 o = *(float2*)(outp + (size_t)node * 2);   // self term from gemm0z
        o.x += ax; o.y += ay;
        *(float2*)(outp + (size_t)node * 2) = o;
    }
}

// ---------------- launch ----------------
extern "C" void kernel_launch(void* const* d_in, const int* in_sizes, int n_in,
                              void* d_out, int out_size, void* d_ws, size_t ws_size,
                              hipStream_t stream)
{
    const float* x_tx   = (const float*)d_in[0];
    const float* x_addr = (const float*)d_in[1];
    const int* e_tt = (const int*)d_in[2];
    const int* e_aa = (const int*)d_in[3];
    const int* e_at = (const int*)d_in[4];
    const int* e_ta = (const int*)d_in[5];
    const float* Wl0_tt = (const float*)d_in[6];
    const float* bl0_tt = (const float*)d_in[7];
    const float* Wr0_tt = (const float*)d_in[8];
    const float* Wl0_aa = (const float*)d_in[9];
    const float* bl0_aa = (const float*)d_in[10];
    const float* Wr0_aa = (const float*)d_in[11];
    const float* Wl0_at = (const float*)d_in[12];
    const float* bl0_at = (const float*)d_in[13];
    const float* Wr0_at = (const float*)d_in[14];
    const float* Wl0_ta = (const float*)d_in[15];
    const float* bl0_ta = (const float*)d_in[16];
    const float* Wr0_ta = (const float*)d_in[17];
    const float* Wl1_tt = (const float*)d_in[18];
    const float* bl1_tt = (const float*)d_in[19];
    const float* Wr1_tt = (const float*)d_in[20];
    const float* Wl1_aa = (const float*)d_in[21];
    const float* bl1_aa = (const float*)d_in[22];
    const float* Wr1_aa = (const float*)d_in[23];
    const float* Wl1_at = (const float*)d_in[24];
    const float* bl1_at = (const float*)d_in[25];
    const float* Wr1_at = (const float*)d_in[26];
    const float* Wl1_ta = (const float*)d_in[27];
    const float* bl1_ta = (const float*)d_in[28];
    const float* Wr1_ta = (const float*)d_in[29];

    const int N = in_sizes[0] / DIN;   // 50000
    const int E = in_sizes[2] / 2;     // 400000
    const int nb = (N + 255) >> 8;     // 196 coarse buckets

    size_t off = 0;
    char* base = (char*)d_ws;
    auto alloc = [&](size_t bytes) -> void* {
        void* p = base + off;
        off += (bytes + 255) & ~(size_t)255;
        return p;
    };
    int*   bcnt   = (int*)  alloc((size_t)4 * nb * 4);       // zeroed by memset
    int*   bbase  = (int*)  alloc(((size_t)4 * nb + 1) * 4);
    int*   bcur   = (int*)  alloc((size_t)4 * nb * 4);
    unsigned* tmp = (unsigned*)alloc((size_t)4 * E * 4);
    int*   col    = (int*)  alloc((size_t)4 * E * 4);
    int*   rowptr = (int*)  alloc((size_t)4 * N * 4);
    int*   cnt    = (int*)  alloc((size_t)4 * N * 4);
    unsigned short* xb_tx = (unsigned short*)alloc((size_t)N * DIN * 2);
    unsigned short* xb_ad = (unsigned short*)alloc((size_t)N * DIN * 2);
    uint2* x8_tx = (uint2*)alloc((size_t)N * DIN);
    uint2* x8_ad = (uint2*)alloc((size_t)N * DIN);
    unsigned short* aggb  = (unsigned short*)alloc((size_t)4 * N * DIN * 2);
    float* z      = (float*)alloc((size_t)4 * N * 2 * 4);
    unsigned short* wb_tt  = (unsigned short*)alloc((size_t)DH * DIN * 2);
    unsigned short* wb_aa  = (unsigned short*)alloc((size_t)DH * DIN * 2);
    unsigned short* wb_at  = (unsigned short*)alloc((size_t)DH * DIN * 2);
    unsigned short* wb_ta  = (unsigned short*)alloc((size_t)DH * DIN * 2);
    unsigned short* wr0c_tx = (unsigned short*)alloc((size_t)DH * DIN * 2);
    unsigned short* wr0c_ad = (unsigned short*)alloc((size_t)DH * DIN * 2);
    float* b0c    = (float*)alloc((size_t)2 * DH * 4);
    unsigned short* wzb = (unsigned short*)alloc((size_t)2 * 16 * DH * 2);
    float* b1c    = (float*)alloc((size_t)2 * 2 * 4);
    (void)ws_size;

    float* outp = (float*)d_out;

    // 0. zero bucket counters (tiny)
    hipMemsetAsync(bcnt, 0, (size_t)4 * nb * 4, stream);

    // 1. setup
    {
        int nconv = N * DIN / 8;
        setup_kernel<<<(nconv + 255) / 256, 256, 0, stream>>>(
            x_tx, x_addr,
            Wl0_tt, Wl0_aa, Wl0_at, Wl0_ta,
            Wr0_tt, Wr0_aa, Wr0_at, Wr0_ta,
            bl0_tt, bl0_aa, bl0_at, bl0_ta,
            Wl1_tt, Wl1_aa, Wl1_at, Wl1_ta,
            Wr1_tt, Wr1_aa, Wr1_at, Wr1_ta,
            bl1_tt, bl1_aa, bl1_at, bl1_ta,
            xb_tx, xb_ad, x8_tx, x8_ad,
            wb_tt, wb_aa, wb_at, wb_ta, wr0c_tx, wr0c_ad,
            b0c, wzb, b1c, N);
    }
    // 2. K1: coarse histogram
    {
        dim3 g((E + 4095) / 4096, 4);
        bhist_kernel<<<g, 256, 0, stream>>>(e_tt, e_aa, e_at, e_ta, bcnt, E, nb);
    }
    // 3. K2: scan 4*nb bucket counts
    bscan_kernel<<<1, 1024, 0, stream>>>(bcnt, bbase, bcur, 4 * nb);
    // 4. K3: scatter to buckets
    {
        dim3 g((E + 4095) / 4096, 4);
        bscatter_kernel<<<g, 256, 0, stream>>>(e_tt, e_aa, e_at, e_ta, bcur, tmp, E, nb);
    }
    // 5. K4: per-bucket grouping -> col, rowptr, cnt
    {
        dim3 g(nb, 4);
        bgroup_kernel<<<g, 256, 0, stream>>>(tmp, bbase, col, rowptr, cnt, N, nb);
    }
    // 6. aggregation (fp8 gather, 8 lanes/task)
    {
        dim3 g((N + 31) / 32, 4);
        agg_kernel<<<g, 256, 0, stream>>>((const uint4*)x8_tx, (const uint4*)x8_ad,
                                          rowptr, cnt, col, aggb, N);
    }
    // 7. gemm0 + fused layer-1 transform
    {
        dim3 g((N + 63) / 64, 2);
        gemm0z_kernel<<<g, 256, 0, stream>>>(
            xb_tx, xb_ad, aggb,
            wb_tt, wb_at, wr0c_tx, wb_aa, wb_ta, wr0c_ad,
            b0c, wzb, b1c, z, outp, N);
    }
    // 8. layer-1 aggregation
    {
        dim3 g((N + 31) / 32, 2);
        l1_agg_kernel<<<g, 256, 0, stream>>>(rowptr, cnt, col, z, outp, N);
    }
}